// Round 11
// baseline (178.408 us; speedup 1.0000x reference)
//
#include <hip/hip_runtime.h>
#include <cmath>

#define Tn  2048
#define Cn  1024
#define Hn  64
#define BTn 16384

typedef _Float16 f16x8 __attribute__((ext_vector_type(8)));
typedef _Float16 f16x4 __attribute__((ext_vector_type(4)));
typedef _Float16 f16x2 __attribute__((ext_vector_type(2)));
typedef float    f32x4 __attribute__((ext_vector_type(4)));

#define MFMA16(a, b, c) __builtin_amdgcn_mfma_f32_16x16x32_f16(a, b, c, 0, 0, 0)

// ---------------------------------------------------------------------------
// prep: transpose Wq|Wk|Wv (each [Cn][64] fp32) into Wt[192][Cn] f16
// ---------------------------------------------------------------------------
__global__ __launch_bounds__(256) void prep_w_kernel(
    const float* __restrict__ Wq, const float* __restrict__ Wk,
    const float* __restrict__ Wv, _Float16* __restrict__ Wt)
{
    __shared__ float ts[64][65];
    const int blk = blockIdx.x;          // 48 = 3 proj * 16 c-tiles
    const int p   = blk >> 4;
    const int c0  = (blk & 15) * 64;
    const float* __restrict__ W = (p == 0) ? Wq : (p == 1) ? Wk : Wv;
    const int tid = threadIdx.x;
    #pragma unroll
    for (int it = 0; it < 16; it++) {
        int idx = tid + it * 256;
        int c = idx >> 6, n = idx & 63;
        ts[c][n] = W[(size_t)(c0 + c) * Hn + n];
    }
    __syncthreads();
    #pragma unroll
    for (int it = 0; it < 16; it++) {
        int idx = tid + it * 256;
        int n = idx >> 6, c = idx & 63;
        Wt[(size_t)(p * 64 + n) * Cn + c0 + c] = (_Float16)ts[c][n];
    }
}

// ---------------------------------------------------------------------------
// proj, round-11: ZERO-STAGING. Every staged variant (R0-R10) sat at 43+-2us
// regardless of schedule, VGPR, occupancy<=16 waves/CU, or input bytes (R9:
// half the bytes, same time). The only kernel shapes hitting ~6 TB/s on this
// chip (xcast, fillBuffer) have 32 waves/CU, no LDS tile, no barriers. This
// variant deletes the x LDS tile, the stage phase, and all pre-combine
// barriers: A-frags come DIRECTLY from global fp32 (two f32x4 per frag;
// 16 rows x 32 B; the 4 col-group waves re-read the same lines -> L1/L2
// absorb, HBM still reads x once) with VALU f32->f16 convert feeding MFMA.
// LDS = 24.6 KB combine buffer only -> 4 blocks/CU x 8 waves = 32 waves/CU
// (2x TLP of every prior variant). Wave = (kh, wc): kh = K-half, wc = col
// group of 48; acc[2][3]; K-half partials combined via LDS; epilogue
// (RoPE, q pre-scaled H^-1/2, vT[b][h][t] transpose) unchanged.
// ---------------------------------------------------------------------------
__global__ __launch_bounds__(512) void proj_kernel(
    const float* __restrict__ x, const _Float16* __restrict__ Wt,
    _Float16* __restrict__ qh, _Float16* __restrict__ kh_out, _Float16* __restrict__ vT)
{
    __shared__ __align__(16) f32x4 pbuf[6 * 256];   // 24.6 KB -> 4 blocks/CU
    const int row0 = blockIdx.x * 32;
    const int tid  = threadIdx.x;
    const int wave = tid >> 6, lane = tid & 63;
    const int kh   = wave >> 2;          // K-half
    const int wc   = wave & 3;           // col group (48 cols)
    const int quad = lane >> 4, l15 = lane & 15;

    f32x4 acc[2][3] = {};
    const _Float16* __restrict__ wb = Wt + (size_t)(wc * 48 + l15) * Cn
                                         + kh * 512 + quad * 8;
    const float* __restrict__ xr0 = x + (size_t)(row0 +      l15) * Cn
                                      + kh * 512 + quad * 8;
    const float* __restrict__ xr1 = x + (size_t)(row0 + 16 + l15) * Cn
                                      + kh * 512 + quad * 8;

    #pragma unroll
    for (int kc = 0; kc < 16; kc++) {
        const int kf = kc * 32;
        f16x8 b0 = *(const f16x8*)&wb[kf];
        f16x8 b1 = *(const f16x8*)&wb[16 * Cn + kf];
        f16x8 b2 = *(const f16x8*)&wb[32 * Cn + kf];
        f32x4 l0 = *(const f32x4*)&xr0[kf];
        f32x4 h0 = *(const f32x4*)&xr0[kf + 4];
        f32x4 l1 = *(const f32x4*)&xr1[kf];
        f32x4 h1 = *(const f32x4*)&xr1[kf + 4];
        f16x8 a0, a1;
        a0[0] = (_Float16)l0[0]; a0[1] = (_Float16)l0[1];
        a0[2] = (_Float16)l0[2]; a0[3] = (_Float16)l0[3];
        a0[4] = (_Float16)h0[0]; a0[5] = (_Float16)h0[1];
        a0[6] = (_Float16)h0[2]; a0[7] = (_Float16)h0[3];
        a1[0] = (_Float16)l1[0]; a1[1] = (_Float16)l1[1];
        a1[2] = (_Float16)l1[2]; a1[3] = (_Float16)l1[3];
        a1[4] = (_Float16)h1[0]; a1[5] = (_Float16)h1[1];
        a1[6] = (_Float16)h1[2]; a1[7] = (_Float16)h1[3];
        acc[0][0] = MFMA16(a0, b0, acc[0][0]);
        acc[1][0] = MFMA16(a1, b0, acc[1][0]);
        acc[0][1] = MFMA16(a0, b1, acc[0][1]);
        acc[1][1] = MFMA16(a1, b1, acc[1][1]);
        acc[0][2] = MFMA16(a0, b2, acc[0][2]);
        acc[1][2] = MFMA16(a1, b2, acc[1][2]);
    }

    // Combine the two K-halves: waves kh=1 dump partials into LDS, waves
    // kh=0 add them. Lane-major f32x4 layout = conflict-free.
    if (kh) {
        #pragma unroll
        for (int mt = 0; mt < 2; mt++)
            #pragma unroll
            for (int nt = 0; nt < 3; nt++)
                pbuf[(mt * 3 + nt) * 256 + wc * 64 + lane] = acc[mt][nt];
    }
    __syncthreads();
    if (kh) return;
    #pragma unroll
    for (int mt = 0; mt < 2; mt++)
        #pragma unroll
        for (int nt = 0; nt < 3; nt++)
            acc[mt][nt] += pbuf[(mt * 3 + nt) * 256 + wc * 64 + lane];

    // Epilogue (waves 0-3; wc owns cols [wc*48, wc*48+48))
    const int bidx = row0 >> 11;
    #pragma unroll
    for (int nt = 0; nt < 3; nt++) {
        const int n = wc * 48 + nt * 16 + l15;
        const int p = n >> 6;            // uniform per (wc,nt)
        const int h = n & 63;
        if (p < 2) {                     // q or k: RoPE
            _Float16* __restrict__ outb = (p == 0) ? qh : kh_out;
            const float invf = __expf(-0.2878231366242557f * (float)(h >> 1));
            #pragma unroll
            for (int mt = 0; mt < 2; mt++) {
                #pragma unroll
                for (int r = 0; r < 4; r++) {
                    int   row = row0 + mt * 16 + quad * 4 + r;
                    float val = acc[mt][nt][r];
                    float partner = __shfl_xor(val, 1, 64);
                    float ang = (float)(row & (Tn - 1)) * invf;
                    float sv, cv;
                    __sincosf(ang, &sv, &cv);
                    float res = (h & 1) ? fmaf(val, cv,  partner * sv)
                                        : fmaf(val, cv, -partner * sv);
                    if (p == 0) res *= 0.125f;
                    float resn = __shfl_xor(res, 1, 64);
                    if (!(l15 & 1)) {
                        f16x2 pk = { (_Float16)res, (_Float16)resn };
                        *(f16x2*)&outb[(size_t)row * Hn + h] = pk;
                    }
                }
            }
        } else {                         // v: store transposed vT[b][h][t]
            #pragma unroll
            for (int mt = 0; mt < 2; mt++) {
                int t = (row0 & (Tn - 1)) + mt * 16 + quad * 4;
                f16x4 pv = { (_Float16)acc[mt][nt][0], (_Float16)acc[mt][nt][1],
                             (_Float16)acc[mt][nt][2], (_Float16)acc[mt][nt][3] };
                *(f16x4*)&vT[((size_t)bidx * Hn + h) * Tn + t] = pv;
            }
        }
    }
}

// ---------------------------------------------------------------------------
// attn: barrier-free flash loop (EXACT round-2 version, the best measured).
// QT=16, STL=64, 256 thr = 4 waves; each wave processes every 4th s-tile
// with its own online-softmax state; one barrier + LDS merge at the end.
// K and vT B-frags read directly from global (L2-resident, XCD-affine via
// b = blk&7). qt permuted so each CU's resident blocks have constant work.
// Untouched this round: single-variable experiment on proj.
// ---------------------------------------------------------------------------
#define PSP 72

__global__ __launch_bounds__(256, 4) void attn_kernel(
    const _Float16* __restrict__ qh, const _Float16* __restrict__ kh,
    const _Float16* __restrict__ vT, float* __restrict__ out)
{
    __shared__ _Float16 ps[4][16 * PSP];     // wave-private P transpose
    __shared__ float ocomb[4][16][65];
    __shared__ float mlcomb[4][2][16];       // [wave][m|l][row]

    const int blk = blockIdx.x;
    const int b   = blk & 7;                 // batch == XCD affinity
    const int j   = blk >> 3;                // 0..127
    const int jm  = j & 31, g = j >> 5;      // complement permutation:
    const int qt  = (g == 0) ? (127 - jm)    // per-CU resident set sums const
                  : (g == 1) ? (64 + jm)
                  : (g == 2) ? (63 - jm) : jm;
    const int t0  = qt * 16;
    const int tid = threadIdx.x;
    const int w = tid >> 6, lane = tid & 63;
    const int quad = lane >> 4, l15 = lane & 15;

    const _Float16* __restrict__ qb = qh + (size_t)b * Tn * Hn;
    const _Float16* __restrict__ kb = kh + (size_t)b * Tn * Hn;
    const _Float16* __restrict__ vb = vT + (size_t)b * Hn * Tn;

    // Q A-frags: held in registers for the whole loop
    const f16x8 aq0 = *(const f16x8*)&qb[(size_t)(t0 + l15) * Hn +      quad * 8];
    const f16x8 aq1 = *(const f16x8*)&qb[(size_t)(t0 + l15) * Hn + 32 + quad * 8];

    float m_run[4], l_run[4];
    f32x4 oacc[4] = {};
    #pragma unroll
    for (int r = 0; r < 4; r++) { m_run[r] = -1e30f; l_run[r] = 0.0f; }

    const int nst = (t0 + 16 + 63) >> 6;
    for (int jt = w; jt < nst; jt += 4) {
        const int s0 = jt * 64;

        // K B-frags direct from global (16 rows x 64B per load instr)
        f16x8 kf[4][2];
        #pragma unroll
        for (int nt = 0; nt < 4; nt++) {
            const _Float16* kp = &kb[(size_t)(s0 + nt * 16 + l15) * Hn + quad * 8];
            kf[nt][0] = *(const f16x8*)kp;
            kf[nt][1] = *(const f16x8*)(kp + 32);
        }
        f32x4 sacc[4];
        #pragma unroll
        for (int nt = 0; nt < 4; nt++) {
            f32x4 z = {};
            z = MFMA16(aq0, kf[nt][0], z);
            z = MFMA16(aq1, kf[nt][1], z);
            sacc[nt] = z;
        }

        // vT B-frags: issue before softmax (independent), consumed by PV
        f16x8 vf[2][4];
        #pragma unroll
        for (int sc = 0; sc < 2; sc++)
            #pragma unroll
            for (int ht = 0; ht < 4; ht++)
                vf[sc][ht] = *(const f16x8*)&vb[(size_t)(ht * 16 + l15) * Tn
                                                + s0 + sc * 32 + quad * 8];

        if (jt == nst - 1) {             // causal mask: only diagonal tile
            #pragma unroll
            for (int nt = 0; nt < 4; nt++)
                #pragma unroll
                for (int r = 0; r < 4; r++) {
                    int scol = s0 + nt * 16 + l15;
                    int trow = t0 + quad * 4 + r;
                    if (scol > trow) sacc[nt][r] = -1e30f;
                }
        }

        // online softmax (rows = quad*4+r; reduce over the 16 l15 lanes)
        float pr[4][4];
        #pragma unroll
        for (int r = 0; r < 4; r++) {
            float mx = fmaxf(fmaxf(sacc[0][r], sacc[1][r]),
                             fmaxf(sacc[2][r], sacc[3][r]));
            #pragma unroll
            for (int off = 1; off < 16; off <<= 1)
                mx = fmaxf(mx, __shfl_xor(mx, off, 64));
            float mnew  = fmaxf(m_run[r], mx);
            float alpha = __expf(m_run[r] - mnew);
            m_run[r] = mnew;
            float rs = 0.0f;
            #pragma unroll
            for (int nt = 0; nt < 4; nt++) {
                float pv = __expf(sacc[nt][r] - mnew);
                pr[nt][r] = pv; rs += pv;
            }
            #pragma unroll
            for (int off = 1; off < 16; off <<= 1)
                rs += __shfl_xor(rs, off, 64);
            l_run[r] = fmaf(l_run[r], alpha, rs);
            #pragma unroll
            for (int ht = 0; ht < 4; ht++)
                oacc[ht][r] = oacc[ht][r] * alpha;
        }

        // P -> ps (wave-private; same-wave RAW, no barrier)
        #pragma unroll
        for (int nt = 0; nt < 4; nt++)
            #pragma unroll
            for (int r = 0; r < 4; r++) {
                float pv = pr[nt][r];
                float pn = __shfl_xor(pv, 1, 64);
                if (!(l15 & 1)) {
                    f16x2 pk = { (_Float16)pv, (_Float16)pn };
                    *(f16x2*)&ps[w][(quad * 4 + r) * PSP + nt * 16 + l15] = pk;
                }
            }

        // O += P V  (8 MFMA, B-frags already in registers)
        #pragma unroll
        for (int sc = 0; sc < 2; sc++) {
            f16x8 ap = *(const f16x8*)&ps[w][l15 * PSP + sc * 32 + quad * 8];
            #pragma unroll
            for (int ht = 0; ht < 4; ht++)
                oacc[ht] = MFMA16(ap, vf[sc][ht], oacc[ht]);
        }
    }

    // Write partials, barrier, merge the four waves' online-softmax states.
    #pragma unroll
    for (int r = 0; r < 4; r++) {
        #pragma unroll
        for (int ht = 0; ht < 4; ht++)
            ocomb[w][quad * 4 + r][ht * 16 + l15] = oacc[ht][r];
        if (l15 == 0) {
            mlcomb[w][0][quad * 4 + r] = m_run[r];
            mlcomb[w][1][quad * 4 + r] = l_run[r];
        }
    }
    __syncthreads();

    // wave w finalizes rows [w*4, w*4+4); 64 lanes = 64 h (coalesced)
    #pragma unroll
    for (int rp = 0; rp < 4; rp++) {
        int row = w * 4 + rp;
        float m0 = mlcomb[0][0][row], m1 = mlcomb[1][0][row];
        float m2 = mlcomb[2][0][row], m3 = mlcomb[3][0][row];
        float mm = fmaxf(fmaxf(m0, m1), fmaxf(m2, m3));
        float a0 = __expf(m0 - mm), a1 = __expf(m1 - mm);
        float a2 = __expf(m2 - mm), a3 = __expf(m3 - mm);
        float ll = mlcomb[0][1][row] * a0 + mlcomb[1][1][row] * a1
                 + mlcomb[2][1][row] * a2 + mlcomb[3][1][row] * a3;
        float ov = (ocomb[0][row][lane] * a0 + ocomb[1][row][lane] * a1
                  + ocomb[2][row][lane] * a2 + ocomb[3][row][lane] * a3) / ll;
        out[((size_t)b * Tn + t0 + row) * Hn + lane] = ov;
    }
}

extern "C" void kernel_launch(void* const* d_in, const int* in_sizes, int n_in,
                              void* d_out, int out_size, void* d_ws, size_t ws_size,
                              hipStream_t stream) {
    const float* x  = (const float*)d_in[0];
    const float* Wq = (const float*)d_in[1];
    const float* Wk = (const float*)d_in[2];
    const float* Wv = (const float*)d_in[3];

    const size_t qkvN = (size_t)BTn * Hn;
    _Float16* qh = (_Float16*)d_ws;
    _Float16* kh = qh + qkvN;
    _Float16* vT = kh + qkvN;                     // [8][64][2048] transposed
    _Float16* Wt = vT + qkvN;                     // [192][1024] f16

    prep_w_kernel<<<48, 256, 0, stream>>>(Wq, Wk, Wv, Wt);
    proj_kernel<<<BTn / 32, 512, 0, stream>>>(x, Wt, qh, kh, vT);
    attn_kernel<<<1024, 256, 0, stream>>>(qh, kh, vT, (float*)d_out);
}

// Round 12
// 172.629 us; speedup vs baseline: 1.0335x; 1.0335x over previous
//
#include <hip/hip_runtime.h>
#include <cmath>

#define Tn  2048
#define Cn  1024
#define Hn  64
#define BTn 16384

typedef _Float16 f16x8 __attribute__((ext_vector_type(8)));
typedef _Float16 f16x4 __attribute__((ext_vector_type(4)));
typedef _Float16 f16x2 __attribute__((ext_vector_type(2)));
typedef float    f32x4 __attribute__((ext_vector_type(4)));

#define MFMA16(a, b, c) __builtin_amdgcn_mfma_f32_16x16x32_f16(a, b, c, 0, 0, 0)

// ---------------------------------------------------------------------------
// prep: transpose Wq|Wk|Wv (each [Cn][64] fp32) into Wt[192][Cn] f16
// ---------------------------------------------------------------------------
__global__ __launch_bounds__(256) void prep_w_kernel(
    const float* __restrict__ Wq, const float* __restrict__ Wk,
    const float* __restrict__ Wv, _Float16* __restrict__ Wt)
{
    __shared__ float ts[64][65];
    const int blk = blockIdx.x;          // 48 = 3 proj * 16 c-tiles
    const int p   = blk >> 4;
    const int c0  = (blk & 15) * 64;
    const float* __restrict__ W = (p == 0) ? Wq : (p == 1) ? Wk : Wv;
    const int tid = threadIdx.x;
    #pragma unroll
    for (int it = 0; it < 16; it++) {
        int idx = tid + it * 256;
        int c = idx >> 6, n = idx & 63;
        ts[c][n] = W[(size_t)(c0 + c) * Hn + n];
    }
    __syncthreads();
    #pragma unroll
    for (int it = 0; it < 16; it++) {
        int idx = tid + it * 256;
        int n = idx >> 6, c = idx & 63;
        Wt[(size_t)(p * 64 + n) * Cn + c0 + c] = (_Float16)ts[c][n];
    }
}

// ---------------------------------------------------------------------------
// proj, round-12: THE ACTUAL TLP TEST. R11's zero-staging never raised TLP
// (grid=512 caps blocks/CU at 2; occupancy stayed 37% -- same as every
// variant since R2). Every proj variant ever measured ran at 16 waves/CU
// and landed at 43+-2 us; the only fast-streaming kernels on this chip
// (xcast, fillBuffer) run at 32 waves/CU. This variant doubles TLP via the
// GRID: 1024 blocks x 16 rows (was 512 x 32). Block = 16 rows x 192 cols,
// 512 thr = 8 waves = (kh = K-half) x (wc = col group of 48); each wave
// acc[1][3] over its K-half. LDS = 16 x 1032 f16 = 33 KB -> thread-capped
// 4 blocks/CU x 8 waves = 32 waves/CU. Staged K-loop otherwise the proven
// R2 shape (stage -> one barrier -> 16 kc of {3 Wt L2-loads, 1 LDS read,
// 3 MFMA}). Cost accepted: Wt L2 traffic doubles to 384 MB (L2-resident,
// ~0.6 TB/s/XCD today, headroom exists). x HBM traffic unchanged.
// Partials combined via LDS (reuse xs); epilogue RoPE (q pre-scaled
// H^-1/2) + vT[b][h][t] transpose, mt-loop dropped (single m-tile).
// ---------------------------------------------------------------------------
#define XSP 1032

__global__ __launch_bounds__(512) void proj_kernel(
    const float* __restrict__ x, const _Float16* __restrict__ Wt,
    _Float16* __restrict__ qh, _Float16* __restrict__ kh_out, _Float16* __restrict__ vT)
{
    __shared__ __align__(16) _Float16 xs[16 * XSP];   // 33 KB; 4 blk/CU (thread cap)
    const int row0 = blockIdx.x * 16;
    const int tid  = threadIdx.x;
    const int wave = tid >> 6, lane = tid & 63;
    const int kh   = wave >> 2;          // K-half
    const int wc   = wave & 3;           // col group (48 cols)
    const int quad = lane >> 4, l15 = lane & 15;

    // Stage x (16 rows x 1024 fp32 -> f16): 4096 float4, 8 per thread,
    // all in flight.
    {
        float4 xv[8];
        #pragma unroll
        for (int it = 0; it < 8; it++) {
            int idx = tid + it * 512;
            int r = idx >> 8, c4 = idx & 255;
            xv[it] = *(const float4*)&x[(size_t)(row0 + r) * Cn + c4 * 4];
        }
        #pragma unroll
        for (int it = 0; it < 8; it++) {
            int idx = tid + it * 512;
            int r = idx >> 8, c4 = idx & 255;
            f16x4 hv = { (_Float16)xv[it].x, (_Float16)xv[it].y,
                         (_Float16)xv[it].z, (_Float16)xv[it].w };
            *(f16x4*)&xs[r * XSP + c4 * 4] = hv;
        }
    }
    __syncthreads();

    f32x4 acc[3] = {};
    const _Float16* __restrict__ wb = Wt + (size_t)(wc * 48 + l15) * Cn
                                         + kh * 512 + quad * 8;
    const _Float16* __restrict__ xp = &xs[kh * 512 + quad * 8];

    #pragma unroll 4
    for (int kc = 0; kc < 16; kc++) {
        const int kf = kc * 32;
        f16x8 b0 = *(const f16x8*)&wb[kf];
        f16x8 b1 = *(const f16x8*)&wb[16 * Cn + kf];
        f16x8 b2 = *(const f16x8*)&wb[32 * Cn + kf];
        f16x8 a0 = *(const f16x8*)&xp[l15 * XSP + kf];
        acc[0] = MFMA16(a0, b0, acc[0]);
        acc[1] = MFMA16(a0, b1, acc[1]);
        acc[2] = MFMA16(a0, b2, acc[2]);
    }

    // Combine the two K-halves: waves kh=1 dump partials into LDS (reuse
    // xs), waves kh=0 add them. Lane-major f32x4 = conflict-free.
    __syncthreads();                     // everyone done reading xs
    f32x4* __restrict__ pbuf = (f32x4*)xs;      // 3*256*16B = 12.3 KB
    if (kh) {
        #pragma unroll
        for (int nt = 0; nt < 3; nt++)
            pbuf[nt * 256 + wc * 64 + lane] = acc[nt];
    }
    __syncthreads();
    if (kh) return;
    #pragma unroll
    for (int nt = 0; nt < 3; nt++)
        acc[nt] += pbuf[nt * 256 + wc * 64 + lane];

    // Epilogue (waves 0-3; wc owns cols [wc*48, wc*48+48); 16 rows)
    const int bidx = row0 >> 11;
    #pragma unroll
    for (int nt = 0; nt < 3; nt++) {
        const int n = wc * 48 + nt * 16 + l15;
        const int p = n >> 6;            // uniform per (wc,nt)
        const int h = n & 63;
        if (p < 2) {                     // q or k: RoPE
            _Float16* __restrict__ outb = (p == 0) ? qh : kh_out;
            const float invf = __expf(-0.2878231366242557f * (float)(h >> 1));
            #pragma unroll
            for (int r = 0; r < 4; r++) {
                int   row = row0 + quad * 4 + r;
                float val = acc[nt][r];
                float partner = __shfl_xor(val, 1, 64);
                float ang = (float)(row & (Tn - 1)) * invf;
                float sv, cv;
                __sincosf(ang, &sv, &cv);
                float res = (h & 1) ? fmaf(val, cv,  partner * sv)
                                    : fmaf(val, cv, -partner * sv);
                if (p == 0) res *= 0.125f;
                float resn = __shfl_xor(res, 1, 64);
                if (!(l15 & 1)) {
                    f16x2 pk = { (_Float16)res, (_Float16)resn };
                    *(f16x2*)&outb[(size_t)row * Hn + h] = pk;
                }
            }
        } else {                         // v: store transposed vT[b][h][t]
            int t = (row0 & (Tn - 1)) + quad * 4;
            f16x4 pv = { (_Float16)acc[nt][0], (_Float16)acc[nt][1],
                         (_Float16)acc[nt][2], (_Float16)acc[nt][3] };
            *(f16x4*)&vT[((size_t)bidx * Hn + h) * Tn + t] = pv;
        }
    }
}

// ---------------------------------------------------------------------------
// attn: barrier-free flash loop (EXACT round-2 version, the best measured).
// QT=16, STL=64, 256 thr = 4 waves; each wave processes every 4th s-tile
// with its own online-softmax state; one barrier + LDS merge at the end.
// K and vT B-frags read directly from global (L2-resident, XCD-affine via
// b = blk&7). qt permuted so each CU's resident blocks have constant work.
// Untouched this round: single-variable experiment on proj.
// ---------------------------------------------------------------------------
#define PSP 72

__global__ __launch_bounds__(256, 4) void attn_kernel(
    const _Float16* __restrict__ qh, const _Float16* __restrict__ kh,
    const _Float16* __restrict__ vT, float* __restrict__ out)
{
    __shared__ _Float16 ps[4][16 * PSP];     // wave-private P transpose
    __shared__ float ocomb[4][16][65];
    __shared__ float mlcomb[4][2][16];       // [wave][m|l][row]

    const int blk = blockIdx.x;
    const int b   = blk & 7;                 // batch == XCD affinity
    const int j   = blk >> 3;                // 0..127
    const int jm  = j & 31, g = j >> 5;      // complement permutation:
    const int qt  = (g == 0) ? (127 - jm)    // per-CU resident set sums const
                  : (g == 1) ? (64 + jm)
                  : (g == 2) ? (63 - jm) : jm;
    const int t0  = qt * 16;
    const int tid = threadIdx.x;
    const int w = tid >> 6, lane = tid & 63;
    const int quad = lane >> 4, l15 = lane & 15;

    const _Float16* __restrict__ qb = qh + (size_t)b * Tn * Hn;
    const _Float16* __restrict__ kb = kh + (size_t)b * Tn * Hn;
    const _Float16* __restrict__ vb = vT + (size_t)b * Hn * Tn;

    // Q A-frags: held in registers for the whole loop
    const f16x8 aq0 = *(const f16x8*)&qb[(size_t)(t0 + l15) * Hn +      quad * 8];
    const f16x8 aq1 = *(const f16x8*)&qb[(size_t)(t0 + l15) * Hn + 32 + quad * 8];

    float m_run[4], l_run[4];
    f32x4 oacc[4] = {};
    #pragma unroll
    for (int r = 0; r < 4; r++) { m_run[r] = -1e30f; l_run[r] = 0.0f; }

    const int nst = (t0 + 16 + 63) >> 6;
    for (int jt = w; jt < nst; jt += 4) {
        const int s0 = jt * 64;

        // K B-frags direct from global (16 rows x 64B per load instr)
        f16x8 kf[4][2];
        #pragma unroll
        for (int nt = 0; nt < 4; nt++) {
            const _Float16* kp = &kb[(size_t)(s0 + nt * 16 + l15) * Hn + quad * 8];
            kf[nt][0] = *(const f16x8*)kp;
            kf[nt][1] = *(const f16x8*)(kp + 32);
        }
        f32x4 sacc[4];
        #pragma unroll
        for (int nt = 0; nt < 4; nt++) {
            f32x4 z = {};
            z = MFMA16(aq0, kf[nt][0], z);
            z = MFMA16(aq1, kf[nt][1], z);
            sacc[nt] = z;
        }

        // vT B-frags: issue before softmax (independent), consumed by PV
        f16x8 vf[2][4];
        #pragma unroll
        for (int sc = 0; sc < 2; sc++)
            #pragma unroll
            for (int ht = 0; ht < 4; ht++)
                vf[sc][ht] = *(const f16x8*)&vb[(size_t)(ht * 16 + l15) * Tn
                                                + s0 + sc * 32 + quad * 8];

        if (jt == nst - 1) {             // causal mask: only diagonal tile
            #pragma unroll
            for (int nt = 0; nt < 4; nt++)
                #pragma unroll
                for (int r = 0; r < 4; r++) {
                    int scol = s0 + nt * 16 + l15;
                    int trow = t0 + quad * 4 + r;
                    if (scol > trow) sacc[nt][r] = -1e30f;
                }
        }

        // online softmax (rows = quad*4+r; reduce over the 16 l15 lanes)
        float pr[4][4];
        #pragma unroll
        for (int r = 0; r < 4; r++) {
            float mx = fmaxf(fmaxf(sacc[0][r], sacc[1][r]),
                             fmaxf(sacc[2][r], sacc[3][r]));
            #pragma unroll
            for (int off = 1; off < 16; off <<= 1)
                mx = fmaxf(mx, __shfl_xor(mx, off, 64));
            float mnew  = fmaxf(m_run[r], mx);
            float alpha = __expf(m_run[r] - mnew);
            m_run[r] = mnew;
            float rs = 0.0f;
            #pragma unroll
            for (int nt = 0; nt < 4; nt++) {
                float pv = __expf(sacc[nt][r] - mnew);
                pr[nt][r] = pv; rs += pv;
            }
            #pragma unroll
            for (int off = 1; off < 16; off <<= 1)
                rs += __shfl_xor(rs, off, 64);
            l_run[r] = fmaf(l_run[r], alpha, rs);
            #pragma unroll
            for (int ht = 0; ht < 4; ht++)
                oacc[ht][r] = oacc[ht][r] * alpha;
        }

        // P -> ps (wave-private; same-wave RAW, no barrier)
        #pragma unroll
        for (int nt = 0; nt < 4; nt++)
            #pragma unroll
            for (int r = 0; r < 4; r++) {
                float pv = pr[nt][r];
                float pn = __shfl_xor(pv, 1, 64);
                if (!(l15 & 1)) {
                    f16x2 pk = { (_Float16)pv, (_Float16)pn };
                    *(f16x2*)&ps[w][(quad * 4 + r) * PSP + nt * 16 + l15] = pk;
                }
            }

        // O += P V  (8 MFMA, B-frags already in registers)
        #pragma unroll
        for (int sc = 0; sc < 2; sc++) {
            f16x8 ap = *(const f16x8*)&ps[w][l15 * PSP + sc * 32 + quad * 8];
            #pragma unroll
            for (int ht = 0; ht < 4; ht++)
                oacc[ht] = MFMA16(ap, vf[sc][ht], oacc[ht]);
        }
    }

    // Write partials, barrier, merge the four waves' online-softmax states.
    #pragma unroll
    for (int r = 0; r < 4; r++) {
        #pragma unroll
        for (int ht = 0; ht < 4; ht++)
            ocomb[w][quad * 4 + r][ht * 16 + l15] = oacc[ht][r];
        if (l15 == 0) {
            mlcomb[w][0][quad * 4 + r] = m_run[r];
            mlcomb[w][1][quad * 4 + r] = l_run[r];
        }
    }
    __syncthreads();

    // wave w finalizes rows [w*4, w*4+4); 64 lanes = 64 h (coalesced)
    #pragma unroll
    for (int rp = 0; rp < 4; rp++) {
        int row = w * 4 + rp;
        float m0 = mlcomb[0][0][row], m1 = mlcomb[1][0][row];
        float m2 = mlcomb[2][0][row], m3 = mlcomb[3][0][row];
        float mm = fmaxf(fmaxf(m0, m1), fmaxf(m2, m3));
        float a0 = __expf(m0 - mm), a1 = __expf(m1 - mm);
        float a2 = __expf(m2 - mm), a3 = __expf(m3 - mm);
        float ll = mlcomb[0][1][row] * a0 + mlcomb[1][1][row] * a1
                 + mlcomb[2][1][row] * a2 + mlcomb[3][1][row] * a3;
        float ov = (ocomb[0][row][lane] * a0 + ocomb[1][row][lane] * a1
                  + ocomb[2][row][lane] * a2 + ocomb[3][row][lane] * a3) / ll;
        out[((size_t)b * Tn + t0 + row) * Hn + lane] = ov;
    }
}

extern "C" void kernel_launch(void* const* d_in, const int* in_sizes, int n_in,
                              void* d_out, int out_size, void* d_ws, size_t ws_size,
                              hipStream_t stream) {
    const float* x  = (const float*)d_in[0];
    const float* Wq = (const float*)d_in[1];
    const float* Wk = (const float*)d_in[2];
    const float* Wv = (const float*)d_in[3];

    const size_t qkvN = (size_t)BTn * Hn;
    _Float16* qh = (_Float16*)d_ws;
    _Float16* kh = qh + qkvN;
    _Float16* vT = kh + qkvN;                     // [8][64][2048] transposed
    _Float16* Wt = vT + qkvN;                     // [192][1024] f16

    prep_w_kernel<<<48, 256, 0, stream>>>(Wq, Wk, Wv, Wt);
    proj_kernel<<<BTn / 16, 512, 0, stream>>>(x, Wt, qh, kh, vT);
    attn_kernel<<<1024, 256, 0, stream>>>(qh, kh, vT, (float*)d_out);
}

// Round 13
// 158.844 us; speedup vs baseline: 1.1232x; 1.0868x over previous
//
#include <hip/hip_runtime.h>
#include <cmath>

#define Tn  2048
#define Cn  1024
#define Hn  64
#define BTn 16384

typedef _Float16 f16x8 __attribute__((ext_vector_type(8)));
typedef _Float16 f16x4 __attribute__((ext_vector_type(4)));
typedef _Float16 f16x2 __attribute__((ext_vector_type(2)));
typedef float    f32x4 __attribute__((ext_vector_type(4)));

#define MFMA16(a, b, c) __builtin_amdgcn_mfma_f32_16x16x32_f16(a, b, c, 0, 0, 0)

// ---------------------------------------------------------------------------
// prep: transpose Wq|Wk|Wv (each [Cn][64] fp32) into Wt[192][Cn] f16
// ---------------------------------------------------------------------------
__global__ __launch_bounds__(256) void prep_w_kernel(
    const float* __restrict__ Wq, const float* __restrict__ Wk,
    const float* __restrict__ Wv, _Float16* __restrict__ Wt)
{
    __shared__ float ts[64][65];
    const int blk = blockIdx.x;          // 48 = 3 proj * 16 c-tiles
    const int p   = blk >> 4;
    const int c0  = (blk & 15) * 64;
    const float* __restrict__ W = (p == 0) ? Wq : (p == 1) ? Wk : Wv;
    const int tid = threadIdx.x;
    #pragma unroll
    for (int it = 0; it < 16; it++) {
        int idx = tid + it * 256;
        int c = idx >> 6, n = idx & 63;
        ts[c][n] = W[(size_t)(c0 + c) * Hn + n];
    }
    __syncthreads();
    #pragma unroll
    for (int it = 0; it < 16; it++) {
        int idx = tid + it * 256;
        int n = idx >> 6, c = idx & 63;
        Wt[(size_t)(p * 64 + n) * Cn + c0 + c] = (_Float16)ts[c][n];
    }
}

// ---------------------------------------------------------------------------
// proj, round-13: STEP-AMORTIZATION. Evidence across 12 rounds: time tracks
// exposed-latency steps per output, not occupancy (R1 2w/SIMD=45, R2 4w=43,
// R12 5w+1:1 ratio=60) -- the compiler always minimizes VGPR and serializes
// loads, so each kc step costs ~1 L2 latency regardless of schedule. Lever:
// amortize each step over more output. 64-row blocks, grid 256 = exactly
// 1 block/CU: total exposed steps HALVE vs R7, Wt L2 traffic halves
// (384 KB/CU), and the x stage is one 256 KB/CU burst (16 indep float4
// loads/thread x 16 waves in flight, ONE barrier) -- the closest staged
// shape to the 6 TB/s xcast/fillBuffer pattern. Block = 1024 thr = 16
// waves = (kh: K-half) x (mh: row-half) x (wc: col group of 48); each wave
// keeps the proven acc[2][3] / 2:1 MFMA:B inner shape over its K-half.
// LDS 64 x 1032 f16 = 129 KB dynamic (hipFuncSetAttribute). K-half
// partials combined via LDS (reused); epilogue RoPE (q pre-scaled H^-1/2)
// + vT[b][h][t] transpose per (mh, wc).
// ---------------------------------------------------------------------------
#define XSP 1032

__global__ __launch_bounds__(1024) void proj_kernel(
    const float* __restrict__ x, const _Float16* __restrict__ Wt,
    _Float16* __restrict__ qh, _Float16* __restrict__ kh_out, _Float16* __restrict__ vT)
{
    extern __shared__ __align__(16) char smem[];      // 64*XSP*2 = 129 KB
    _Float16* xs = (_Float16*)smem;
    const int blk  = blockIdx.x;
    const int tid  = threadIdx.x;
    const int wave = tid >> 6, lane = tid & 63;
    const int kh   = wave >> 3;          // K-half
    const int mh   = (wave >> 2) & 1;    // row-half (32 rows)
    const int wc   = wave & 3;           // col group (48 cols)
    const int quad = lane >> 4, l15 = lane & 15;
    const int row0 = blk * 64 + mh * 32; // this wave's 32-row base

    // Stage x (64 rows x 1024 fp32 -> f16): 16384 float4, 16 per thread,
    // all independent and in flight; ONE barrier.
    {
        float4 xv[16];
        #pragma unroll
        for (int it = 0; it < 16; it++) {
            int idx = tid + it * 1024;
            int r = idx >> 8, c4 = idx & 255;
            xv[it] = *(const float4*)&x[(size_t)(blk * 64 + r) * Cn + c4 * 4];
        }
        #pragma unroll
        for (int it = 0; it < 16; it++) {
            int idx = tid + it * 1024;
            int r = idx >> 8, c4 = idx & 255;
            f16x4 hv = { (_Float16)xv[it].x, (_Float16)xv[it].y,
                         (_Float16)xv[it].z, (_Float16)xv[it].w };
            *(f16x4*)&xs[r * XSP + c4 * 4] = hv;
        }
    }
    __syncthreads();

    f32x4 acc[2][3] = {};
    const _Float16* __restrict__ wb = Wt + (size_t)(wc * 48 + l15) * Cn
                                         + kh * 512 + quad * 8;
    const _Float16* __restrict__ xp = &xs[(mh * 32) * XSP + kh * 512 + quad * 8];

    #pragma unroll 4
    for (int kc = 0; kc < 16; kc++) {
        const int kf = kc * 32;
        f16x8 b0 = *(const f16x8*)&wb[kf];
        f16x8 b1 = *(const f16x8*)&wb[16 * Cn + kf];
        f16x8 b2 = *(const f16x8*)&wb[32 * Cn + kf];
        f16x8 a0 = *(const f16x8*)&xp[(     l15) * XSP + kf];
        f16x8 a1 = *(const f16x8*)&xp[(16 + l15) * XSP + kf];
        acc[0][0] = MFMA16(a0, b0, acc[0][0]);
        acc[1][0] = MFMA16(a1, b0, acc[1][0]);
        acc[0][1] = MFMA16(a0, b1, acc[0][1]);
        acc[1][1] = MFMA16(a1, b1, acc[1][1]);
        acc[0][2] = MFMA16(a0, b2, acc[0][2]);
        acc[1][2] = MFMA16(a1, b2, acc[1][2]);
    }

    // Combine the two K-halves per (mh, wc): kh=1 waves dump partials into
    // LDS (reuse xs; 8 groups x 6 acc x 64 lanes x 16 B = 48 KB), kh=0
    // waves add. Lane-major f32x4 = conflict-free.
    __syncthreads();                     // everyone done reading xs
    f32x4* __restrict__ pbuf = (f32x4*)smem;
    const int gidx = (mh * 4 + wc) * 6;
    if (kh) {
        #pragma unroll
        for (int mt = 0; mt < 2; mt++)
            #pragma unroll
            for (int nt = 0; nt < 3; nt++)
                pbuf[(gidx + mt * 3 + nt) * 64 + lane] = acc[mt][nt];
    }
    __syncthreads();
    if (kh) return;
    #pragma unroll
    for (int mt = 0; mt < 2; mt++)
        #pragma unroll
        for (int nt = 0; nt < 3; nt++)
            acc[mt][nt] += pbuf[(gidx + mt * 3 + nt) * 64 + lane];

    // Epilogue (kh=0 waves; (mh, wc) owns rows [row0, row0+32) x cols
    // [wc*48, wc*48+48))
    const int bidx = (blk * 64) >> 11;
    #pragma unroll
    for (int nt = 0; nt < 3; nt++) {
        const int n = wc * 48 + nt * 16 + l15;
        const int p = n >> 6;            // uniform per (wc,nt)
        const int h = n & 63;
        if (p < 2) {                     // q or k: RoPE
            _Float16* __restrict__ outb = (p == 0) ? qh : kh_out;
            const float invf = __expf(-0.2878231366242557f * (float)(h >> 1));
            #pragma unroll
            for (int mt = 0; mt < 2; mt++) {
                #pragma unroll
                for (int r = 0; r < 4; r++) {
                    int   row = row0 + mt * 16 + quad * 4 + r;
                    float val = acc[mt][nt][r];
                    float partner = __shfl_xor(val, 1, 64);
                    float ang = (float)(row & (Tn - 1)) * invf;
                    float sv, cv;
                    __sincosf(ang, &sv, &cv);
                    float res = (h & 1) ? fmaf(val, cv,  partner * sv)
                                        : fmaf(val, cv, -partner * sv);
                    if (p == 0) res *= 0.125f;
                    float resn = __shfl_xor(res, 1, 64);
                    if (!(l15 & 1)) {
                        f16x2 pk = { (_Float16)res, (_Float16)resn };
                        *(f16x2*)&outb[(size_t)row * Hn + h] = pk;
                    }
                }
            }
        } else {                         // v: store transposed vT[b][h][t]
            #pragma unroll
            for (int mt = 0; mt < 2; mt++) {
                int t = (row0 & (Tn - 1)) + mt * 16 + quad * 4;
                f16x4 pv = { (_Float16)acc[mt][nt][0], (_Float16)acc[mt][nt][1],
                             (_Float16)acc[mt][nt][2], (_Float16)acc[mt][nt][3] };
                *(f16x4*)&vT[((size_t)bidx * Hn + h) * Tn + t] = pv;
            }
        }
    }
}

// ---------------------------------------------------------------------------
// attn: barrier-free flash loop (EXACT round-2 version, the best measured).
// QT=16, STL=64, 256 thr = 4 waves; each wave processes every 4th s-tile
// with its own online-softmax state; one barrier + LDS merge at the end.
// K and vT B-frags read directly from global (L2-resident, XCD-affine via
// b = blk&7). qt permuted so each CU's resident blocks have constant work.
// Untouched this round: single-variable experiment on proj.
// ---------------------------------------------------------------------------
#define PSP 72

__global__ __launch_bounds__(256, 4) void attn_kernel(
    const _Float16* __restrict__ qh, const _Float16* __restrict__ kh,
    const _Float16* __restrict__ vT, float* __restrict__ out)
{
    __shared__ _Float16 ps[4][16 * PSP];     // wave-private P transpose
    __shared__ float ocomb[4][16][65];
    __shared__ float mlcomb[4][2][16];       // [wave][m|l][row]

    const int blk = blockIdx.x;
    const int b   = blk & 7;                 // batch == XCD affinity
    const int j   = blk >> 3;                // 0..127
    const int jm  = j & 31, g = j >> 5;      // complement permutation:
    const int qt  = (g == 0) ? (127 - jm)    // per-CU resident set sums const
                  : (g == 1) ? (64 + jm)
                  : (g == 2) ? (63 - jm) : jm;
    const int t0  = qt * 16;
    const int tid = threadIdx.x;
    const int w = tid >> 6, lane = tid & 63;
    const int quad = lane >> 4, l15 = lane & 15;

    const _Float16* __restrict__ qb = qh + (size_t)b * Tn * Hn;
    const _Float16* __restrict__ kb = kh + (size_t)b * Tn * Hn;
    const _Float16* __restrict__ vb = vT + (size_t)b * Hn * Tn;

    // Q A-frags: held in registers for the whole loop
    const f16x8 aq0 = *(const f16x8*)&qb[(size_t)(t0 + l15) * Hn +      quad * 8];
    const f16x8 aq1 = *(const f16x8*)&qb[(size_t)(t0 + l15) * Hn + 32 + quad * 8];

    float m_run[4], l_run[4];
    f32x4 oacc[4] = {};
    #pragma unroll
    for (int r = 0; r < 4; r++) { m_run[r] = -1e30f; l_run[r] = 0.0f; }

    const int nst = (t0 + 16 + 63) >> 6;
    for (int jt = w; jt < nst; jt += 4) {
        const int s0 = jt * 64;

        // K B-frags direct from global (16 rows x 64B per load instr)
        f16x8 kf[4][2];
        #pragma unroll
        for (int nt = 0; nt < 4; nt++) {
            const _Float16* kp = &kb[(size_t)(s0 + nt * 16 + l15) * Hn + quad * 8];
            kf[nt][0] = *(const f16x8*)kp;
            kf[nt][1] = *(const f16x8*)(kp + 32);
        }
        f32x4 sacc[4];
        #pragma unroll
        for (int nt = 0; nt < 4; nt++) {
            f32x4 z = {};
            z = MFMA16(aq0, kf[nt][0], z);
            z = MFMA16(aq1, kf[nt][1], z);
            sacc[nt] = z;
        }

        // vT B-frags: issue before softmax (independent), consumed by PV
        f16x8 vf[2][4];
        #pragma unroll
        for (int sc = 0; sc < 2; sc++)
            #pragma unroll
            for (int ht = 0; ht < 4; ht++)
                vf[sc][ht] = *(const f16x8*)&vb[(size_t)(ht * 16 + l15) * Tn
                                                + s0 + sc * 32 + quad * 8];

        if (jt == nst - 1) {             // causal mask: only diagonal tile
            #pragma unroll
            for (int nt = 0; nt < 4; nt++)
                #pragma unroll
                for (int r = 0; r < 4; r++) {
                    int scol = s0 + nt * 16 + l15;
                    int trow = t0 + quad * 4 + r;
                    if (scol > trow) sacc[nt][r] = -1e30f;
                }
        }

        // online softmax (rows = quad*4+r; reduce over the 16 l15 lanes)
        float pr[4][4];
        #pragma unroll
        for (int r = 0; r < 4; r++) {
            float mx = fmaxf(fmaxf(sacc[0][r], sacc[1][r]),
                             fmaxf(sacc[2][r], sacc[3][r]));
            #pragma unroll
            for (int off = 1; off < 16; off <<= 1)
                mx = fmaxf(mx, __shfl_xor(mx, off, 64));
            float mnew  = fmaxf(m_run[r], mx);
            float alpha = __expf(m_run[r] - mnew);
            m_run[r] = mnew;
            float rs = 0.0f;
            #pragma unroll
            for (int nt = 0; nt < 4; nt++) {
                float pv = __expf(sacc[nt][r] - mnew);
                pr[nt][r] = pv; rs += pv;
            }
            #pragma unroll
            for (int off = 1; off < 16; off <<= 1)
                rs += __shfl_xor(rs, off, 64);
            l_run[r] = fmaf(l_run[r], alpha, rs);
            #pragma unroll
            for (int ht = 0; ht < 4; ht++)
                oacc[ht][r] = oacc[ht][r] * alpha;
        }

        // P -> ps (wave-private; same-wave RAW, no barrier)
        #pragma unroll
        for (int nt = 0; nt < 4; nt++)
            #pragma unroll
            for (int r = 0; r < 4; r++) {
                float pv = pr[nt][r];
                float pn = __shfl_xor(pv, 1, 64);
                if (!(l15 & 1)) {
                    f16x2 pk = { (_Float16)pv, (_Float16)pn };
                    *(f16x2*)&ps[w][(quad * 4 + r) * PSP + nt * 16 + l15] = pk;
                }
            }

        // O += P V  (8 MFMA, B-frags already in registers)
        #pragma unroll
        for (int sc = 0; sc < 2; sc++) {
            f16x8 ap = *(const f16x8*)&ps[w][l15 * PSP + sc * 32 + quad * 8];
            #pragma unroll
            for (int ht = 0; ht < 4; ht++)
                oacc[ht] = MFMA16(ap, vf[sc][ht], oacc[ht]);
        }
    }

    // Write partials, barrier, merge the four waves' online-softmax states.
    #pragma unroll
    for (int r = 0; r < 4; r++) {
        #pragma unroll
        for (int ht = 0; ht < 4; ht++)
            ocomb[w][quad * 4 + r][ht * 16 + l15] = oacc[ht][r];
        if (l15 == 0) {
            mlcomb[w][0][quad * 4 + r] = m_run[r];
            mlcomb[w][1][quad * 4 + r] = l_run[r];
        }
    }
    __syncthreads();

    // wave w finalizes rows [w*4, w*4+4); 64 lanes = 64 h (coalesced)
    #pragma unroll
    for (int rp = 0; rp < 4; rp++) {
        int row = w * 4 + rp;
        float m0 = mlcomb[0][0][row], m1 = mlcomb[1][0][row];
        float m2 = mlcomb[2][0][row], m3 = mlcomb[3][0][row];
        float mm = fmaxf(fmaxf(m0, m1), fmaxf(m2, m3));
        float a0 = __expf(m0 - mm), a1 = __expf(m1 - mm);
        float a2 = __expf(m2 - mm), a3 = __expf(m3 - mm);
        float ll = mlcomb[0][1][row] * a0 + mlcomb[1][1][row] * a1
                 + mlcomb[2][1][row] * a2 + mlcomb[3][1][row] * a3;
        float ov = (ocomb[0][row][lane] * a0 + ocomb[1][row][lane] * a1
                  + ocomb[2][row][lane] * a2 + ocomb[3][row][lane] * a3) / ll;
        out[((size_t)b * Tn + t0 + row) * Hn + lane] = ov;
    }
}

extern "C" void kernel_launch(void* const* d_in, const int* in_sizes, int n_in,
                              void* d_out, int out_size, void* d_ws, size_t ws_size,
                              hipStream_t stream) {
    const float* x  = (const float*)d_in[0];
    const float* Wq = (const float*)d_in[1];
    const float* Wk = (const float*)d_in[2];
    const float* Wv = (const float*)d_in[3];

    const size_t qkvN = (size_t)BTn * Hn;
    _Float16* qh = (_Float16*)d_ws;
    _Float16* kh = qh + qkvN;
    _Float16* vT = kh + qkvN;                     // [8][64][2048] transposed
    _Float16* Wt = vT + qkvN;                     // [192][1024] f16

    const int ldsBytes = 64 * XSP * 2;            // 132096 B dynamic LDS
    static bool attrSet = false;
    if (!attrSet) {
        hipFuncSetAttribute((const void*)proj_kernel,
                            hipFuncAttributeMaxDynamicSharedMemorySize, ldsBytes);
        attrSet = true;
    }

    prep_w_kernel<<<48, 256, 0, stream>>>(Wq, Wk, Wv, Wt);
    proj_kernel<<<BTn / 64, 1024, ldsBytes, stream>>>(x, Wt, qh, kh, vT);
    attn_kernel<<<1024, 256, 0, stream>>>(qh, kh, vT, (float*)d_out);
}

// Round 14
// 155.948 us; speedup vs baseline: 1.1440x; 1.0186x over previous
//
#include <hip/hip_runtime.h>
#include <cmath>

#define Tn  2048
#define Cn  1024
#define Hn  64
#define BTn 16384

typedef _Float16 f16x8 __attribute__((ext_vector_type(8)));
typedef _Float16 f16x4 __attribute__((ext_vector_type(4)));
typedef _Float16 f16x2 __attribute__((ext_vector_type(2)));
typedef float    f32x4 __attribute__((ext_vector_type(4)));

#define MFMA16(a, b, c) __builtin_amdgcn_mfma_f32_16x16x32_f16(a, b, c, 0, 0, 0)

// ---------------------------------------------------------------------------
// prep: transpose Wq|Wk|Wv (each [Cn][64] fp32) into Wt[192][Cn] f16
// ---------------------------------------------------------------------------
__global__ __launch_bounds__(256) void prep_w_kernel(
    const float* __restrict__ Wq, const float* __restrict__ Wk,
    const float* __restrict__ Wv, _Float16* __restrict__ Wt)
{
    __shared__ float ts[64][65];
    const int blk = blockIdx.x;          // 48 = 3 proj * 16 c-tiles
    const int p   = blk >> 4;
    const int c0  = (blk & 15) * 64;
    const float* __restrict__ W = (p == 0) ? Wq : (p == 1) ? Wk : Wv;
    const int tid = threadIdx.x;
    #pragma unroll
    for (int it = 0; it < 16; it++) {
        int idx = tid + it * 256;
        int c = idx >> 6, n = idx & 63;
        ts[c][n] = W[(size_t)(c0 + c) * Hn + n];
    }
    __syncthreads();
    #pragma unroll
    for (int it = 0; it < 16; it++) {
        int idx = tid + it * 256;
        int n = idx >> 6, c = idx & 63;
        Wt[(size_t)(p * 64 + n) * Cn + c0 + c] = (_Float16)ts[c][n];
    }
}

// ---------------------------------------------------------------------------
// proj, round-14: INLINE-ASM COUNTED-VMCNT PIPELINE. Model after 13 rounds:
// time is flight-depth-limited x/Wt ingestion (~1.5 TB/s effective vs the
// same array streaming at 5.9 TB/s in R9's xcast). hipcc always re-sinks
// source-level prefetch (VGPR<=64 in all 7 variants) -> per-CU in-flight
// bytes ~2-6 KB < the ~9 KB needed to cover HBM latency. Escape (guide
// T3/T4, AITER/HK): asm volatile loads + counted s_waitcnt vmcnt(N) --
// the compiler cannot re-sink them or insert its own vmcnt(0).
//   stage: 16 global_load_dwordx4 issued via asm, ALL in flight, one
//          vmcnt(0), convert fp32->f16, write LDS (XSP stride), barrier.
//   K-loop: rolling 4-slot window of Wt B-frags (3 asm loads/step, 12
//          outstanding steady-state), wait vmcnt(9) -- NEVER 0 -- then
//          sched_barrier(0) (rule: MFMA hoists past asm waits otherwise),
//          then 6 MFMA on the retired slot. Macro-unrolled: literal slots.
// Skeleton = proven R7: 512 blocks x 512 thr, 32-row tiles, wave=(kh,wc),
// acc[2][3], K-half combine via LDS, RoPE/vT epilogue unchanged.
// ---------------------------------------------------------------------------
#define XSP 1032

__global__ __launch_bounds__(512) void proj_kernel(
    const float* __restrict__ x, const _Float16* __restrict__ Wt,
    _Float16* __restrict__ qh, _Float16* __restrict__ kh_out, _Float16* __restrict__ vT)
{
    __shared__ __align__(16) _Float16 xs[32 * XSP];   // 66 KB -> 2 blocks/CU
    const int row0 = blockIdx.x * 32;
    const int tid  = threadIdx.x;
    const int wave = tid >> 6, lane = tid & 63;
    const int kh   = wave >> 2;          // K-half
    const int wc   = wave & 3;           // col group (48 cols)
    const int quad = lane >> 4, l15 = lane & 15;

    // ---- stage: 16 asm loads, all in flight, one drain ----
    {
        f32x4 xv[16];
        #pragma unroll
        for (int it = 0; it < 16; it++) {
            int idx = tid + it * 512;
            int r = idx >> 8, c4 = idx & 255;
            const float* ap = &x[(size_t)(row0 + r) * Cn + c4 * 4];
            asm volatile("global_load_dwordx4 %0, %1, off"
                         : "=v"(xv[it]) : "v"(ap));
        }
        asm volatile("s_waitcnt vmcnt(0)" ::: "memory");
        __builtin_amdgcn_sched_barrier(0);
        #pragma unroll
        for (int it = 0; it < 16; it++) {
            int idx = tid + it * 512;
            int r = idx >> 8, c4 = idx & 255;
            f16x4 hv = { (_Float16)xv[it][0], (_Float16)xv[it][1],
                         (_Float16)xv[it][2], (_Float16)xv[it][3] };
            *(f16x4*)&xs[r * XSP + c4 * 4] = hv;
        }
    }
    __syncthreads();

    f32x4 acc[2][3] = {};
    const _Float16* __restrict__ wb0 = Wt + (size_t)(wc * 48 + l15) * Cn
                                          + kh * 512 + quad * 8;
    const _Float16* __restrict__ wb1 = wb0 + 16 * Cn;
    const _Float16* __restrict__ wb2 = wb0 + 32 * Cn;
    const _Float16* __restrict__ xp  = &xs[kh * 512 + quad * 8];

    f16x8 bb[4][3];

    // issue the 3 Wt B-frag loads of step kcn into slot kcn&3
    #define ISSUE_STEP(kcn)  {                                                 \
        asm volatile("global_load_dwordx4 %0, %1, off"                         \
                     : "=v"(bb[(kcn) & 3][0]) : "v"(wb0 + (kcn) * 32));        \
        asm volatile("global_load_dwordx4 %0, %1, off"                         \
                     : "=v"(bb[(kcn) & 3][1]) : "v"(wb1 + (kcn) * 32));        \
        asm volatile("global_load_dwordx4 %0, %1, off"                         \
                     : "=v"(bb[(kcn) & 3][2]) : "v"(wb2 + (kcn) * 32)); }

    // consume step kcn: wait until its loads retired (NWAIT = 3 * future
    // steps still in flight; 9 steady-state, 6/3/0 in the tail)
    #define COMPUTE_STEP(kcn, NWAIT)  {                                        \
        f16x8 a0 = *(const f16x8*)&xp[(     l15) * XSP + (kcn) * 32];          \
        f16x8 a1 = *(const f16x8*)&xp[(16 + l15) * XSP + (kcn) * 32];          \
        asm volatile("s_waitcnt vmcnt(" #NWAIT ")" ::: "memory");              \
        __builtin_amdgcn_sched_barrier(0);                                     \
        acc[0][0] = MFMA16(a0, bb[(kcn) & 3][0], acc[0][0]);                   \
        acc[1][0] = MFMA16(a1, bb[(kcn) & 3][0], acc[1][0]);                   \
        acc[0][1] = MFMA16(a0, bb[(kcn) & 3][1], acc[0][1]);                   \
        acc[1][1] = MFMA16(a1, bb[(kcn) & 3][1], acc[1][1]);                   \
        acc[0][2] = MFMA16(a0, bb[(kcn) & 3][2], acc[0][2]);                   \
        acc[1][2] = MFMA16(a1, bb[(kcn) & 3][2], acc[1][2]); }

    ISSUE_STEP(0)  ISSUE_STEP(1)  ISSUE_STEP(2)
    ISSUE_STEP(3)  COMPUTE_STEP(0, 9)
    ISSUE_STEP(4)  COMPUTE_STEP(1, 9)
    ISSUE_STEP(5)  COMPUTE_STEP(2, 9)
    ISSUE_STEP(6)  COMPUTE_STEP(3, 9)
    ISSUE_STEP(7)  COMPUTE_STEP(4, 9)
    ISSUE_STEP(8)  COMPUTE_STEP(5, 9)
    ISSUE_STEP(9)  COMPUTE_STEP(6, 9)
    ISSUE_STEP(10) COMPUTE_STEP(7, 9)
    ISSUE_STEP(11) COMPUTE_STEP(8, 9)
    ISSUE_STEP(12) COMPUTE_STEP(9, 9)
    ISSUE_STEP(13) COMPUTE_STEP(10, 9)
    ISSUE_STEP(14) COMPUTE_STEP(11, 9)
    ISSUE_STEP(15) COMPUTE_STEP(12, 9)
    COMPUTE_STEP(13, 6)
    COMPUTE_STEP(14, 3)
    COMPUTE_STEP(15, 0)

    #undef ISSUE_STEP
    #undef COMPUTE_STEP

    // Combine the two K-halves: waves kh=1 dump partials into LDS (reuse
    // xs), waves kh=0 add them. Lane-major f32x4 = conflict-free.
    __syncthreads();                     // everyone done reading xs
    f32x4* __restrict__ pbuf = (f32x4*)xs;      // 6*256*16B = 24.6 KB
    if (kh) {
        #pragma unroll
        for (int mt = 0; mt < 2; mt++)
            #pragma unroll
            for (int nt = 0; nt < 3; nt++)
                pbuf[(mt * 3 + nt) * 256 + wc * 64 + lane] = acc[mt][nt];
    }
    __syncthreads();
    if (kh) return;
    #pragma unroll
    for (int mt = 0; mt < 2; mt++)
        #pragma unroll
        for (int nt = 0; nt < 3; nt++)
            acc[mt][nt] += pbuf[(mt * 3 + nt) * 256 + wc * 64 + lane];

    // Epilogue (waves 0-3; wc owns cols [wc*48, wc*48+48))
    const int bidx = row0 >> 11;
    #pragma unroll
    for (int nt = 0; nt < 3; nt++) {
        const int n = wc * 48 + nt * 16 + l15;
        const int p = n >> 6;            // uniform per (wc,nt)
        const int h = n & 63;
        if (p < 2) {                     // q or k: RoPE
            _Float16* __restrict__ outb = (p == 0) ? qh : kh_out;
            const float invf = __expf(-0.2878231366242557f * (float)(h >> 1));
            #pragma unroll
            for (int mt = 0; mt < 2; mt++) {
                #pragma unroll
                for (int r = 0; r < 4; r++) {
                    int   row = row0 + mt * 16 + quad * 4 + r;
                    float val = acc[mt][nt][r];
                    float partner = __shfl_xor(val, 1, 64);
                    float ang = (float)(row & (Tn - 1)) * invf;
                    float sv, cv;
                    __sincosf(ang, &sv, &cv);
                    float res = (h & 1) ? fmaf(val, cv,  partner * sv)
                                        : fmaf(val, cv, -partner * sv);
                    if (p == 0) res *= 0.125f;
                    float resn = __shfl_xor(res, 1, 64);
                    if (!(l15 & 1)) {
                        f16x2 pk = { (_Float16)res, (_Float16)resn };
                        *(f16x2*)&outb[(size_t)row * Hn + h] = pk;
                    }
                }
            }
        } else {                         // v: store transposed vT[b][h][t]
            #pragma unroll
            for (int mt = 0; mt < 2; mt++) {
                int t = (row0 & (Tn - 1)) + mt * 16 + quad * 4;
                f16x4 pv = { (_Float16)acc[mt][nt][0], (_Float16)acc[mt][nt][1],
                             (_Float16)acc[mt][nt][2], (_Float16)acc[mt][nt][3] };
                *(f16x4*)&vT[((size_t)bidx * Hn + h) * Tn + t] = pv;
            }
        }
    }
}

// ---------------------------------------------------------------------------
// attn: barrier-free flash loop (EXACT round-2 version, the best measured).
// QT=16, STL=64, 256 thr = 4 waves; each wave processes every 4th s-tile
// with its own online-softmax state; one barrier + LDS merge at the end.
// K and vT B-frags read directly from global (L2-resident, XCD-affine via
// b = blk&7). qt permuted so each CU's resident blocks have constant work.
// Untouched this round: single-variable experiment on proj.
// ---------------------------------------------------------------------------
#define PSP 72

__global__ __launch_bounds__(256, 4) void attn_kernel(
    const _Float16* __restrict__ qh, const _Float16* __restrict__ kh,
    const _Float16* __restrict__ vT, float* __restrict__ out)
{
    __shared__ _Float16 ps[4][16 * PSP];     // wave-private P transpose
    __shared__ float ocomb[4][16][65];
    __shared__ float mlcomb[4][2][16];       // [wave][m|l][row]

    const int blk = blockIdx.x;
    const int b   = blk & 7;                 // batch == XCD affinity
    const int j   = blk >> 3;                // 0..127
    const int jm  = j & 31, g = j >> 5;      // complement permutation:
    const int qt  = (g == 0) ? (127 - jm)    // per-CU resident set sums const
                  : (g == 1) ? (64 + jm)
                  : (g == 2) ? (63 - jm) : jm;
    const int t0  = qt * 16;
    const int tid = threadIdx.x;
    const int w = tid >> 6, lane = tid & 63;
    const int quad = lane >> 4, l15 = lane & 15;

    const _Float16* __restrict__ qb = qh + (size_t)b * Tn * Hn;
    const _Float16* __restrict__ kb = kh + (size_t)b * Tn * Hn;
    const _Float16* __restrict__ vb = vT + (size_t)b * Hn * Tn;

    // Q A-frags: held in registers for the whole loop
    const f16x8 aq0 = *(const f16x8*)&qb[(size_t)(t0 + l15) * Hn +      quad * 8];
    const f16x8 aq1 = *(const f16x8*)&qb[(size_t)(t0 + l15) * Hn + 32 + quad * 8];

    float m_run[4], l_run[4];
    f32x4 oacc[4] = {};
    #pragma unroll
    for (int r = 0; r < 4; r++) { m_run[r] = -1e30f; l_run[r] = 0.0f; }

    const int nst = (t0 + 16 + 63) >> 6;
    for (int jt = w; jt < nst; jt += 4) {
        const int s0 = jt * 64;

        // K B-frags direct from global (16 rows x 64B per load instr)
        f16x8 kf[4][2];
        #pragma unroll
        for (int nt = 0; nt < 4; nt++) {
            const _Float16* kp = &kb[(size_t)(s0 + nt * 16 + l15) * Hn + quad * 8];
            kf[nt][0] = *(const f16x8*)kp;
            kf[nt][1] = *(const f16x8*)(kp + 32);
        }
        f32x4 sacc[4];
        #pragma unroll
        for (int nt = 0; nt < 4; nt++) {
            f32x4 z = {};
            z = MFMA16(aq0, kf[nt][0], z);
            z = MFMA16(aq1, kf[nt][1], z);
            sacc[nt] = z;
        }

        // vT B-frags: issue before softmax (independent), consumed by PV
        f16x8 vf[2][4];
        #pragma unroll
        for (int sc = 0; sc < 2; sc++)
            #pragma unroll
            for (int ht = 0; ht < 4; ht++)
                vf[sc][ht] = *(const f16x8*)&vb[(size_t)(ht * 16 + l15) * Tn
                                                + s0 + sc * 32 + quad * 8];

        if (jt == nst - 1) {             // causal mask: only diagonal tile
            #pragma unroll
            for (int nt = 0; nt < 4; nt++)
                #pragma unroll
                for (int r = 0; r < 4; r++) {
                    int scol = s0 + nt * 16 + l15;
                    int trow = t0 + quad * 4 + r;
                    if (scol > trow) sacc[nt][r] = -1e30f;
                }
        }

        // online softmax (rows = quad*4+r; reduce over the 16 l15 lanes)
        float pr[4][4];
        #pragma unroll
        for (int r = 0; r < 4; r++) {
            float mx = fmaxf(fmaxf(sacc[0][r], sacc[1][r]),
                             fmaxf(sacc[2][r], sacc[3][r]));
            #pragma unroll
            for (int off = 1; off < 16; off <<= 1)
                mx = fmaxf(mx, __shfl_xor(mx, off, 64));
            float mnew  = fmaxf(m_run[r], mx);
            float alpha = __expf(m_run[r] - mnew);
            m_run[r] = mnew;
            float rs = 0.0f;
            #pragma unroll
            for (int nt = 0; nt < 4; nt++) {
                float pv = __expf(sacc[nt][r] - mnew);
                pr[nt][r] = pv; rs += pv;
            }
            #pragma unroll
            for (int off = 1; off < 16; off <<= 1)
                rs += __shfl_xor(rs, off, 64);
            l_run[r] = fmaf(l_run[r], alpha, rs);
            #pragma unroll
            for (int ht = 0; ht < 4; ht++)
                oacc[ht][r] = oacc[ht][r] * alpha;
        }

        // P -> ps (wave-private; same-wave RAW, no barrier)
        #pragma unroll
        for (int nt = 0; nt < 4; nt++)
            #pragma unroll
            for (int r = 0; r < 4; r++) {
                float pv = pr[nt][r];
                float pn = __shfl_xor(pv, 1, 64);
                if (!(l15 & 1)) {
                    f16x2 pk = { (_Float16)pv, (_Float16)pn };
                    *(f16x2*)&ps[w][(quad * 4 + r) * PSP + nt * 16 + l15] = pk;
                }
            }

        // O += P V  (8 MFMA, B-frags already in registers)
        #pragma unroll
        for (int sc = 0; sc < 2; sc++) {
            f16x8 ap = *(const f16x8*)&ps[w][l15 * PSP + sc * 32 + quad * 8];
            #pragma unroll
            for (int ht = 0; ht < 4; ht++)
                oacc[ht] = MFMA16(ap, vf[sc][ht], oacc[ht]);
        }
    }

    // Write partials, barrier, merge the four waves' online-softmax states.
    #pragma unroll
    for (int r = 0; r < 4; r++) {
        #pragma unroll
        for (int ht = 0; ht < 4; ht++)
            ocomb[w][quad * 4 + r][ht * 16 + l15] = oacc[ht][r];
        if (l15 == 0) {
            mlcomb[w][0][quad * 4 + r] = m_run[r];
            mlcomb[w][1][quad * 4 + r] = l_run[r];
        }
    }
    __syncthreads();

    // wave w finalizes rows [w*4, w*4+4); 64 lanes = 64 h (coalesced)
    #pragma unroll
    for (int rp = 0; rp < 4; rp++) {
        int row = w * 4 + rp;
        float m0 = mlcomb[0][0][row], m1 = mlcomb[1][0][row];
        float m2 = mlcomb[2][0][row], m3 = mlcomb[3][0][row];
        float mm = fmaxf(fmaxf(m0, m1), fmaxf(m2, m3));
        float a0 = __expf(m0 - mm), a1 = __expf(m1 - mm);
        float a2 = __expf(m2 - mm), a3 = __expf(m3 - mm);
        float ll = mlcomb[0][1][row] * a0 + mlcomb[1][1][row] * a1
                 + mlcomb[2][1][row] * a2 + mlcomb[3][1][row] * a3;
        float ov = (ocomb[0][row][lane] * a0 + ocomb[1][row][lane] * a1
                  + ocomb[2][row][lane] * a2 + ocomb[3][row][lane] * a3) / ll;
        out[((size_t)b * Tn + t0 + row) * Hn + lane] = ov;
    }
}

extern "C" void kernel_launch(void* const* d_in, const int* in_sizes, int n_in,
                              void* d_out, int out_size, void* d_ws, size_t ws_size,
                              hipStream_t stream) {
    const float* x  = (const float*)d_in[0];
    const float* Wq = (const float*)d_in[1];
    const float* Wk = (const float*)d_in[2];
    const float* Wv = (const float*)d_in[3];

    const size_t qkvN = (size_t)BTn * Hn;
    _Float16* qh = (_Float16*)d_ws;
    _Float16* kh = qh + qkvN;
    _Float16* vT = kh + qkvN;                     // [8][64][2048] transposed
    _Float16* Wt = vT + qkvN;                     // [192][1024] f16

    prep_w_kernel<<<48, 256, 0, stream>>>(Wq, Wk, Wv, Wt);
    proj_kernel<<<BTn / 32, 512, 0, stream>>>(x, Wt, qh, kh, vT);
    attn_kernel<<<1024, 256, 0, stream>>>(qh, kh, vT, (float*)d_out);
}